// Round 14
// baseline (918.010 us; speedup 1.0000x reference)
//
#include <hip/hip_runtime.h>
#include <hip/hip_fp16.h>

namespace {

constexpr int V_ = 256, K_ = 32, C_ = 256;
constexpr int N_ = V_ * K_;            // 8192 nodes per layer
constexpr int E_ = 32768, PF_ = 4, SF_ = 16, L_ = 5;
constexpr int B_ = 512;                // batch
constexpr int NSLICE = B_ / 8;         // 64 batch slices of 8
constexpr int NCHK = 4;                // node chunks per layer
constexpr int NPB = N_ / NCHK;         // 2048 nodes per block
constexpr int NFLAG = NSLICE * L_;     // 320 sync flags

constexpr int PREP_T  = L_ * N_ * SF_;     // 655360
constexpr int INPUT_T = NSLICE * N_;       // 524288

constexpr float LOG2E = 1.4426950408889634f;
constexpr float LN2   = 0.6931471805599453f;

typedef _Float16 h2v __attribute__((ext_vector_type(2)));  // packed f16

__device__ __forceinline__ uint32_t f2h(float a, float b) {
    __half2 h = __floats2half2_rn(a, b);
    return *reinterpret_cast<uint32_t*>(&h);
}
__device__ __forceinline__ h2v splat2h(uint32_t bits) {
    const _Float16 h = __builtin_bit_cast(_Float16, (unsigned short)(bits & 0xffffu));
    h2v r; r.x = h; r.y = h; return r;
}
__device__ __forceinline__ float2 h2f2(h2v v) {
    return make_float2((float)v.x, (float)v.y);
}
__device__ __forceinline__ h2v u2h(uint32_t u) { return __builtin_bit_cast(h2v, u); }

// ---- setup: zero flags + prep (pcx/lwh, rw folded into layer-4) + input layer ----
__global__ void setup_k(const int* __restrict__ sc,    // [L,N,SF]
                        const int* __restrict__ pc,    // [L,E,PF]
                        const float* __restrict__ lw,  // [L,N,SF]
                        const float* __restrict__ rw,  // [N]
                        const int* __restrict__ inp,   // [B,V]
                        const float* __restrict__ lp,  // [V,K,C]
                        ushort4* __restrict__ pcx,     // [L,N,SF]
                        __half* __restrict__ lwh,      // [L,N,SF]
                        uint4* __restrict__ nm,        // [NSLICE][N]
                        int* __restrict__ flags)       // [NFLAG]
{
    const int t = blockIdx.x * blockDim.x + threadIdx.x;
    if (t < NFLAG) flags[t] = 0;
    if (t < PREP_T) {
        const int l = t >> 17;                         // / (N*SF)
        const int n = (t >> 4) & (N_ - 1);
        const int e = sc[t];
        const int4 p = *reinterpret_cast<const int4*>(pc + ((size_t)l * E_ + e) * 4);
        ushort4 u;
        u.x = (unsigned short)p.x; u.y = (unsigned short)p.y;
        u.z = (unsigned short)p.z; u.w = (unsigned short)p.w;
        pcx[t] = u;
        const float add = (l == L_ - 1) ? rw[n] : 0.f;
        lwh[t] = __float2half((lw[t] + add) * LOG2E);
    } else {
        const int t2 = t - PREP_T;                     // [0, NSLICE*N)
        const int vk = t2 & (N_ - 1);
        const int bs = t2 >> 13;
        const int v = vk >> 5;
        const int b = bs * 8;
        const float* row = lp + (size_t)vk * C_;
        uint4 r;
        r.x = f2h(row[inp[(b + 0) * V_ + v]] * LOG2E, row[inp[(b + 1) * V_ + v]] * LOG2E);
        r.y = f2h(row[inp[(b + 2) * V_ + v]] * LOG2E, row[inp[(b + 3) * V_ + v]] * LOG2E);
        r.z = f2h(row[inp[(b + 4) * V_ + v]] * LOG2E, row[inp[(b + 5) * V_ + v]] * LOG2E);
        r.w = f2h(row[inp[(b + 6) * V_ + v]] * LOG2E, row[inp[(b + 7) * V_ + v]] * LOG2E);
        nm[(size_t)bs * N_ + vk] = r;
    }
}

// one node's 16 children -> m2[4] (packed max), acc[8]
__device__ __forceinline__ void node_lse(const uint4* lds, const uint4* pr, const uint4* wr,
                                         h2v m2[4], float acc[8])
{
    h2v xs[8][4], cm[4];

    auto children8 = [&](const uint4 pw0, const uint4 pw1, const uint4 pw2,
                         const uint4 pw3, const uint4 wv) {
        auto child = [&](int s8, uint32_t rr0, uint32_t rr1, uint32_t wbits) {
            const uint4 a = lds[rr0 & 0xffffu];
            const uint4 b = lds[rr0 >> 16];
            const uint4 c = lds[rr1 & 0xffffu];
            const uint4 d = lds[rr1 >> 16];
            const h2v w2 = splat2h(wbits);
            #pragma unroll
            for (int q = 0; q < 4; ++q) {
                h2v t = (u2h((&a.x)[q]) + u2h((&b.x)[q]))
                      + (u2h((&c.x)[q]) + u2h((&d.x)[q]));
                t = t + w2;
                xs[s8][q] = t;
                cm[q] = __builtin_elementwise_max(cm[q], t);
            }
        };
        child(0, pw0.x, pw0.y, wv.x);
        child(1, pw0.z, pw0.w, wv.x >> 16);
        child(2, pw1.x, pw1.y, wv.y);
        child(3, pw1.z, pw1.w, wv.y >> 16);
        child(4, pw2.x, pw2.y, wv.z);
        child(5, pw2.z, pw2.w, wv.z >> 16);
        child(6, pw3.x, pw3.y, wv.w);
        child(7, pw3.z, pw3.w, wv.w >> 16);
    };

    // ---- half 0 ----
    #pragma unroll
    for (int q = 0; q < 4; ++q) cm[q] = splat2h(0xF400u);  // f16 -16384
    children8(pr[0], pr[1], pr[2], pr[3], wr[0]);
    #pragma unroll
    for (int q = 0; q < 4; ++q) m2[q] = cm[q];
    #pragma unroll
    for (int j = 0; j < 8; ++j) acc[j] = 0.f;
    #pragma unroll
    for (int s = 0; s < 8; ++s) {
        #pragma unroll
        for (int q = 0; q < 4; ++q) {
            const float2 f = h2f2(xs[s][q] - m2[q]);
            acc[2 * q + 0] += exp2f(f.x);
            acc[2 * q + 1] += exp2f(f.y);
        }
    }

    // ---- half 1 ----
    #pragma unroll
    for (int q = 0; q < 4; ++q) cm[q] = splat2h(0xF400u);
    children8(pr[4], pr[5], pr[6], pr[7], wr[1]);
    #pragma unroll
    for (int q = 0; q < 4; ++q) {
        const h2v mm = __builtin_elementwise_max(m2[q], cm[q]);
        const float2 df = h2f2(m2[q] - mm);
        acc[2 * q + 0] *= exp2f(df.x);
        acc[2 * q + 1] *= exp2f(df.y);
        m2[q] = mm;
    }
    #pragma unroll
    for (int s = 0; s < 8; ++s) {
        #pragma unroll
        for (int q = 0; q < 4; ++q) {
            const float2 f = h2f2(xs[s][q] - m2[q]);
            acc[2 * q + 0] += exp2f(f.x);
            acc[2 * q + 1] += exp2f(f.y);
        }
    }
}

__device__ __forceinline__ void stage_slice(uint4* lds, const uint4* src) {
    for (int i = threadIdx.x; i < N_; i += 1024) lds[i] = src[i];
    __syncthreads();
}

// release: all threads fence, then one atomic bump
__device__ __forceinline__ void sig_release(int* f) {
    __threadfence();
    __syncthreads();
    if (threadIdx.x == 0) __hip_atomic_fetch_add(f, 1, __ATOMIC_RELEASE,
                                                 __HIP_MEMORY_SCOPE_AGENT);
}
// acquire: wait for all 4 siblings
__device__ __forceinline__ void sig_wait(int* f) {
    if (threadIdx.x == 0) {
        while (__hip_atomic_load(f, __ATOMIC_ACQUIRE, __HIP_MEMORY_SCOPE_AGENT) < NCHK)
            __builtin_amdgcn_s_sleep(1);
    }
    __syncthreads();
    __threadfence();
}

} // namespace

// ---- persistent mega kernel, PLAIN launch (grid=256=#CUs -> co-resident by capacity;
//      coop launch is NOT used: it cannot be graph-captured and poisons perf) ----
__global__ __launch_bounds__(1024) void mega_k(
    uint4* __restrict__ nm0,         // [NSLICE][N]  (input layer, from setup)
    uint4* __restrict__ nm1,         // [NSLICE][N]  (pong)
    const uint4* __restrict__ pcx,   // [L][N][8]
    const uint4* __restrict__ lwh,   // [L][N][2]
    float* __restrict__ pm,          // [NCHK][B]
    float* __restrict__ ps,          // [NCHK][B]
    float* __restrict__ out,         // [B]
    int* __restrict__ flags)         // [NSLICE][L]
{
    __shared__ uint4 lds[N_];                       // 128 KB
    const int bs = blockIdx.x & (NSLICE - 1);
    const int nc = blockIdx.x >> 6;
    int* fl = flags + bs * L_;

    // ---- layers 0..3 ----
    for (int l = 0; l < L_ - 1; ++l) {
        const uint4* src = ((l & 1) ? nm1 : nm0) + (size_t)bs * N_;
        uint4*       dst = ((l & 1) ? nm0 : nm1) + (size_t)bs * N_;
        const uint4* pcl = pcx + (size_t)l * N_ * 8;
        const uint4* lwl = lwh + (size_t)l * N_ * 2;

        stage_slice(lds, src);

        #pragma unroll
        for (int r = 0; r < 2; ++r) {
            const int n = nc * NPB + r * 1024 + threadIdx.x;
            h2v m2[4];
            float acc[8];
            node_lse(lds, pcl + (size_t)n * 8, lwl + (size_t)n * 2, m2, acc);

            uint4 o;
            {
                const float2 f0 = h2f2(m2[0]);
                const float2 f1 = h2f2(m2[1]);
                o.x = f2h(f0.x + log2f(acc[0]), f0.y + log2f(acc[1]));
                o.y = f2h(f1.x + log2f(acc[2]), f1.y + log2f(acc[3]));
            }
            {
                const float2 f2v = h2f2(m2[2]);
                const float2 f3v = h2f2(m2[3]);
                o.z = f2h(f2v.x + log2f(acc[4]), f2v.y + log2f(acc[5]));
                o.w = f2h(f3v.x + log2f(acc[6]), f3v.y + log2f(acc[7]));
            }
            dst[n] = o;
        }

        sig_release(fl + l);   // my chunk of layer l output is visible
        sig_wait(fl + l);      // all 4 chunks done -> safe to stage next
    }

    // ---- layer 4 fused with root partial (rw folded into lwh) ----
    {
        const int l = L_ - 1;
        const uint4* src = nm0 + (size_t)bs * N_;    // l=3 (odd) wrote nm0
        const uint4* pcl = pcx + (size_t)l * N_ * 8;
        const uint4* lwl = lwh + (size_t)l * N_ * 2;

        stage_slice(lds, src);

        float v0[8];
        {
            const int n = nc * NPB + threadIdx.x;
            h2v m2[4];
            float acc[8];
            node_lse(lds, pcl + (size_t)n * 8, lwl + (size_t)n * 2, m2, acc);
            #pragma unroll
            for (int q = 0; q < 4; ++q) {
                const float2 f = h2f2(m2[q]);
                v0[2 * q + 0] = f.x + log2f(acc[2 * q + 0]);
                v0[2 * q + 1] = f.y + log2f(acc[2 * q + 1]);
            }
        }
        float M[8], S[8];
        {
            const int n = nc * NPB + 1024 + threadIdx.x;
            h2v m2[4];
            float acc[8];
            node_lse(lds, pcl + (size_t)n * 8, lwl + (size_t)n * 2, m2, acc);
            #pragma unroll
            for (int q = 0; q < 4; ++q) {
                const float2 f = h2f2(m2[q]);
                const float v1a = f.x + log2f(acc[2 * q + 0]);
                const float v1b = f.y + log2f(acc[2 * q + 1]);
                M[2 * q + 0] = fmaxf(v0[2 * q + 0], v1a);
                M[2 * q + 1] = fmaxf(v0[2 * q + 1], v1b);
                S[2 * q + 0] = exp2f(v0[2 * q + 0] - M[2 * q + 0]) + exp2f(v1a - M[2 * q + 0]);
                S[2 * q + 1] = exp2f(v0[2 * q + 1] - M[2 * q + 1]) + exp2f(v1b - M[2 * q + 1]);
            }
        }

        // 64-lane butterfly
        for (int d = 1; d < 64; d <<= 1) {
            #pragma unroll
            for (int j = 0; j < 8; ++j) {
                const float om = __shfl_xor(M[j], d);
                const float os = __shfl_xor(S[j], d);
                const float nmax = fmaxf(M[j], om);
                S[j] = S[j] * exp2f(M[j] - nmax) + os * exp2f(om - nmax);
                M[j] = nmax;
            }
        }

        __syncthreads();                             // LDS child-reads done
        float* red = reinterpret_cast<float*>(lds);  // [16][8][2]
        const int wid = threadIdx.x >> 6;
        if ((threadIdx.x & 63) == 0) {
            #pragma unroll
            for (int j = 0; j < 8; ++j) {
                red[(wid * 8 + j) * 2 + 0] = M[j];
                red[(wid * 8 + j) * 2 + 1] = S[j];
            }
        }
        __syncthreads();
        if (threadIdx.x < 8) {
            const int j = threadIdx.x;
            float Mm = -3.0e38f, Ss = 0.f;
            for (int w = 0; w < 16; ++w) {
                const float m_ = red[(w * 8 + j) * 2 + 0];
                const float s_ = red[(w * 8 + j) * 2 + 1];
                const float nmax = fmaxf(Mm, m_);
                Ss = Ss * exp2f(Mm - nmax) + s_ * exp2f(m_ - nmax);
                Mm = nmax;
            }
            pm[nc * B_ + bs * 8 + j] = Mm;
            ps[nc * B_ + bs * 8 + j] = Ss;
        }

        sig_release(fl + l);
        if (nc == 0) {
            sig_wait(fl + l);
            if (threadIdx.x < 8) {
                const int b = bs * 8 + threadIdx.x;
                float Mm = -3.0e38f, Ss = 0.f;
                for (int c = 0; c < NCHK; ++c) {
                    const float m_ = pm[c * B_ + b];
                    const float s_ = ps[c * B_ + b];
                    const float nmax = fmaxf(Mm, m_);
                    Ss = Ss * exp2f(Mm - nmax) + s_ * exp2f(m_ - nmax);
                    Mm = nmax;
                }
                out[b] = (Mm + log2f(Ss)) * LN2;
            }
        }
    }
}

extern "C" void kernel_launch(void* const* d_in, const int* in_sizes, int n_in,
                              void* d_out, int out_size, void* d_ws, size_t ws_size,
                              hipStream_t stream) {
    const int*   inp = (const int*)d_in[0];     // [B,V]
    const float* lp  = (const float*)d_in[1];   // [V,K,C]
    const int*   pc  = (const int*)d_in[2];     // [L,E,PF]
    const int*   sc  = (const int*)d_in[3];     // [L,N,SF]
    const float* lw  = (const float*)d_in[4];   // [L,N,SF]
    const float* rw  = (const float*)d_in[5];   // [N]
    float*       out = (float*)d_out;           // [B,1]

    uint4*   nm0 = (uint4*)d_ws;                             // 8 MB
    uint4*   nm1 = nm0 + (size_t)NSLICE * N_;                // 8 MB
    ushort4* pcx = (ushort4*)(nm1 + (size_t)NSLICE * N_);    // 5 MB
    __half*  lwh = (__half*)(pcx + (size_t)L_ * N_ * SF_);   // 1.25 MB
    float*   pm  = (float*)(lwh + (size_t)L_ * N_ * SF_);    // [NCHK][B]
    float*   ps  = pm + (size_t)NCHK * B_;
    int*     flags = (int*)(ps + (size_t)NCHK * B_);         // [NSLICE*L]

    setup_k<<<(PREP_T + INPUT_T) / 256, 256, 0, stream>>>(
        sc, pc, lw, rw, inp, lp, pcx, lwh, nm0, flags);

    mega_k<<<NSLICE * NCHK, 1024, 0, stream>>>(
        nm0, nm1, (const uint4*)pcx, (const uint4*)lwh, pm, ps, out, flags);
}

// Round 15
// 168.376 us; speedup vs baseline: 5.4521x; 5.4521x over previous
//
#include <hip/hip_runtime.h>
#include <hip/hip_fp16.h>

namespace {

constexpr int V_ = 256, K_ = 32, C_ = 256;
constexpr int N_ = V_ * K_;            // 8192 nodes per layer
constexpr int E_ = 32768, PF_ = 4, SF_ = 16, L_ = 5;
constexpr int B_ = 512;                // batch
constexpr int NSLICE = B_ / 8;         // 64 batch slices of 8
constexpr int NCHK = 4;                // node chunks per layer
constexpr int NPB = N_ / NCHK;         // 2048 nodes per block

constexpr int PREP_T  = L_ * N_ * SF_;     // 655360
constexpr int INPUT_T = NSLICE * N_;       // 524288

constexpr float LOG2E = 1.4426950408889634f;
constexpr float LN2   = 0.6931471805599453f;

typedef _Float16 h2v __attribute__((ext_vector_type(2)));  // packed f16

__device__ __forceinline__ uint32_t f2h(float a, float b) {
    __half2 h = __floats2half2_rn(a, b);
    return *reinterpret_cast<uint32_t*>(&h);
}
__device__ __forceinline__ h2v splat2h(uint32_t bits) {
    const _Float16 h = __builtin_bit_cast(_Float16, (unsigned short)(bits & 0xffffu));
    h2v r; r.x = h; r.y = h; return r;
}
__device__ __forceinline__ float2 h2f2(h2v v) {
    return make_float2((float)v.x, (float)v.y);
}
__device__ __forceinline__ h2v u2h(uint32_t u) { return __builtin_bit_cast(h2v, u); }

// ---- setup: prep (pcx/lwh, rw folded into layer-4) + input layer ----
__global__ void setup_k(const int* __restrict__ sc,    // [L,N,SF]
                        const int* __restrict__ pc,    // [L,E,PF]
                        const float* __restrict__ lw,  // [L,N,SF]
                        const float* __restrict__ rw,  // [N]
                        const int* __restrict__ inp,   // [B,V]
                        const float* __restrict__ lp,  // [V,K,C]
                        ushort4* __restrict__ pcx,     // [L,N,SF]
                        __half* __restrict__ lwh,      // [L,N,SF]
                        uint4* __restrict__ nm)        // [NSLICE][N]
{
    const int t = blockIdx.x * blockDim.x + threadIdx.x;
    if (t < PREP_T) {
        const int l = t >> 17;                         // / (N*SF)
        const int n = (t >> 4) & (N_ - 1);
        const int e = sc[t];
        const int4 p = *reinterpret_cast<const int4*>(pc + ((size_t)l * E_ + e) * 4);
        ushort4 u;
        u.x = (unsigned short)p.x; u.y = (unsigned short)p.y;
        u.z = (unsigned short)p.z; u.w = (unsigned short)p.w;
        pcx[t] = u;
        const float add = (l == L_ - 1) ? rw[n] : 0.f;
        lwh[t] = __float2half((lw[t] + add) * LOG2E);
    } else {
        const int t2 = t - PREP_T;                     // [0, NSLICE*N)
        const int vk = t2 & (N_ - 1);
        const int bs = t2 >> 13;
        const int v = vk >> 5;
        const int b = bs * 8;
        const float* row = lp + (size_t)vk * C_;
        uint4 r;
        r.x = f2h(row[inp[(b + 0) * V_ + v]] * LOG2E, row[inp[(b + 1) * V_ + v]] * LOG2E);
        r.y = f2h(row[inp[(b + 2) * V_ + v]] * LOG2E, row[inp[(b + 3) * V_ + v]] * LOG2E);
        r.z = f2h(row[inp[(b + 4) * V_ + v]] * LOG2E, row[inp[(b + 5) * V_ + v]] * LOG2E);
        r.w = f2h(row[inp[(b + 6) * V_ + v]] * LOG2E, row[inp[(b + 7) * V_ + v]] * LOG2E);
        nm[(size_t)bs * N_ + vk] = r;
    }
}

// stage 128KB slice: async direct-to-LDS if available (lane layout = base + lane*16)
__device__ __forceinline__ void stage_slice(uint4* lds, const uint4* src) {
#if __has_builtin(__builtin_amdgcn_global_load_lds)
    #pragma unroll
    for (int k = 0; k < 8; ++k) {
        const int i = threadIdx.x + k * 1024;
        __builtin_amdgcn_global_load_lds(
            (const __attribute__((address_space(1))) void*)(src + i),
            (__attribute__((address_space(3))) void*)(lds + i), 16, 0, 0);
    }
#else
    #pragma unroll
    for (int k = 0; k < 8; ++k) {
        const int i = threadIdx.x + k * 1024;
        lds[i] = src[i];
    }
#endif
    __syncthreads();   // compiler emits s_waitcnt vmcnt(0) before s_barrier
}

// one node's 16 children (preloaded indices P[8] / weights W[2]) -> m2[4], acc[8]
__device__ __forceinline__ void node_lse(const uint4* lds, const uint4 P[8], const uint4 W[2],
                                         h2v m2[4], float acc[8])
{
    h2v xs[8][4], cm[4];

    auto children8 = [&](const uint4 pw0, const uint4 pw1, const uint4 pw2,
                         const uint4 pw3, const uint4 wv) {
        auto child = [&](int s8, uint32_t rr0, uint32_t rr1, uint32_t wbits) {
            const uint4 a = lds[rr0 & 0xffffu];
            const uint4 b = lds[rr0 >> 16];
            const uint4 c = lds[rr1 & 0xffffu];
            const uint4 d = lds[rr1 >> 16];
            const h2v w2 = splat2h(wbits);
            #pragma unroll
            for (int q = 0; q < 4; ++q) {
                h2v t = (u2h((&a.x)[q]) + u2h((&b.x)[q]))
                      + (u2h((&c.x)[q]) + u2h((&d.x)[q]));
                t = t + w2;
                xs[s8][q] = t;
                cm[q] = __builtin_elementwise_max(cm[q], t);
            }
        };
        child(0, pw0.x, pw0.y, wv.x);
        child(1, pw0.z, pw0.w, wv.x >> 16);
        child(2, pw1.x, pw1.y, wv.y);
        child(3, pw1.z, pw1.w, wv.y >> 16);
        child(4, pw2.x, pw2.y, wv.z);
        child(5, pw2.z, pw2.w, wv.z >> 16);
        child(6, pw3.x, pw3.y, wv.w);
        child(7, pw3.z, pw3.w, wv.w >> 16);
    };

    // ---- half 0 ----
    #pragma unroll
    for (int q = 0; q < 4; ++q) cm[q] = splat2h(0xF400u);  // f16 -16384
    children8(P[0], P[1], P[2], P[3], W[0]);
    #pragma unroll
    for (int q = 0; q < 4; ++q) m2[q] = cm[q];
    #pragma unroll
    for (int j = 0; j < 8; ++j) acc[j] = 0.f;
    #pragma unroll
    for (int s = 0; s < 8; ++s) {
        #pragma unroll
        for (int q = 0; q < 4; ++q) {
            const float2 f = h2f2(xs[s][q] - m2[q]);
            acc[2 * q + 0] += exp2f(f.x);
            acc[2 * q + 1] += exp2f(f.y);
        }
    }

    // ---- half 1 ----
    #pragma unroll
    for (int q = 0; q < 4; ++q) cm[q] = splat2h(0xF400u);
    children8(P[4], P[5], P[6], P[7], W[1]);
    #pragma unroll
    for (int q = 0; q < 4; ++q) {
        const h2v mm = __builtin_elementwise_max(m2[q], cm[q]);
        const float2 df = h2f2(m2[q] - mm);
        acc[2 * q + 0] *= exp2f(df.x);
        acc[2 * q + 1] *= exp2f(df.y);
        m2[q] = mm;
    }
    #pragma unroll
    for (int s = 0; s < 8; ++s) {
        #pragma unroll
        for (int q = 0; q < 4; ++q) {
            const float2 f = h2f2(xs[s][q] - m2[q]);
            acc[2 * q + 0] += exp2f(f.x);
            acc[2 * q + 1] += exp2f(f.y);
        }
    }
}

__device__ __forceinline__ void load_node_meta(const uint4* pcx, const uint4* lwh, int n,
                                               uint4 P[8], uint4 W[2])
{
    const uint4* pr = pcx + (size_t)n * 8;
    const uint4* wr = lwh + (size_t)n * 2;
    #pragma unroll
    for (int i = 0; i < 8; ++i) P[i] = pr[i];
    W[0] = wr[0]; W[1] = wr[1];
}

// ---- fused layer (layers 0..3), LDS-staged nm slice ----
__global__ __launch_bounds__(1024) void layer_k(
    const uint4* __restrict__ nmi,   // [NSLICE][N] rows of 8 f16 (log2 domain)
    const uint4* __restrict__ pcx,   // [N][8]
    const uint4* __restrict__ lwh,   // [N][2]
    uint4* __restrict__ nmo)         // [NSLICE][N]
{
    __shared__ uint4 lds[N_];                       // 128 KB
    const int bs = blockIdx.x & (NSLICE - 1);
    const int nc = blockIdx.x >> 6;
    const int n0 = nc * NPB + threadIdx.x;
    const int n1 = n0 + 1024;

    // hoist node-0 meta loads above the stage barrier (hide L2 latency)
    uint4 P0[8], W0[2];
    load_node_meta(pcx, lwh, n0, P0, W0);

    stage_slice(lds, nmi + (size_t)bs * N_);

    // issue node-1 meta loads; latency hides under node-0 compute
    uint4 P1[8], W1[2];
    load_node_meta(pcx, lwh, n1, P1, W1);

    #pragma unroll
    for (int r = 0; r < 2; ++r) {
        const int n = r ? n1 : n0;
        h2v m2[4];
        float acc[8];
        node_lse(lds, r ? P1 : P0, r ? W1 : W0, m2, acc);

        uint4 o;
        {
            const float2 f0 = h2f2(m2[0]);
            const float2 f1 = h2f2(m2[1]);
            o.x = f2h(f0.x + log2f(acc[0]), f0.y + log2f(acc[1]));
            o.y = f2h(f1.x + log2f(acc[2]), f1.y + log2f(acc[3]));
        }
        {
            const float2 f2v = h2f2(m2[2]);
            const float2 f3v = h2f2(m2[3]);
            o.z = f2h(f2v.x + log2f(acc[4]), f2v.y + log2f(acc[5]));
            o.w = f2h(f3v.x + log2f(acc[6]), f3v.y + log2f(acc[7]));
        }
        nmo[(size_t)bs * N_ + n] = o;
    }
}

// ---- last layer + root partial (rw folded into lwh; no nm5 materialization) ----
__global__ __launch_bounds__(1024) void layer_last_k(
    const uint4* __restrict__ nmi,   // [NSLICE][N]
    const uint4* __restrict__ pcx,   // [N][8]
    const uint4* __restrict__ lwh,   // [N][2] (includes rw)
    float* __restrict__ pm,          // [NCHK][B]
    float* __restrict__ ps)          // [NCHK][B]
{
    __shared__ uint4 lds[N_];                       // 128 KB
    const int bs = blockIdx.x & (NSLICE - 1);
    const int nc = blockIdx.x >> 6;
    const int n0 = nc * NPB + threadIdx.x;
    const int n1 = n0 + 1024;

    uint4 P0[8], W0[2];
    load_node_meta(pcx, lwh, n0, P0, W0);

    stage_slice(lds, nmi + (size_t)bs * N_);

    uint4 P1[8], W1[2];
    load_node_meta(pcx, lwh, n1, P1, W1);

    // node 0 -> v0[8]
    float v0[8];
    {
        h2v m2[4];
        float acc[8];
        node_lse(lds, P0, W0, m2, acc);
        #pragma unroll
        for (int q = 0; q < 4; ++q) {
            const float2 f = h2f2(m2[q]);
            v0[2 * q + 0] = f.x + log2f(acc[2 * q + 0]);
            v0[2 * q + 1] = f.y + log2f(acc[2 * q + 1]);
        }
    }
    // node 1 -> merge into (M, S)
    float M[8], S[8];
    {
        h2v m2[4];
        float acc[8];
        node_lse(lds, P1, W1, m2, acc);
        #pragma unroll
        for (int q = 0; q < 4; ++q) {
            const float2 f = h2f2(m2[q]);
            const float v1a = f.x + log2f(acc[2 * q + 0]);
            const float v1b = f.y + log2f(acc[2 * q + 1]);
            M[2 * q + 0] = fmaxf(v0[2 * q + 0], v1a);
            M[2 * q + 1] = fmaxf(v0[2 * q + 1], v1b);
            S[2 * q + 0] = exp2f(v0[2 * q + 0] - M[2 * q + 0]) + exp2f(v1a - M[2 * q + 0]);
            S[2 * q + 1] = exp2f(v0[2 * q + 1] - M[2 * q + 1]) + exp2f(v1b - M[2 * q + 1]);
        }
    }

    // 64-lane butterfly reduce
    for (int d = 1; d < 64; d <<= 1) {
        #pragma unroll
        for (int j = 0; j < 8; ++j) {
            const float om = __shfl_xor(M[j], d);
            const float os = __shfl_xor(S[j], d);
            const float nmax = fmaxf(M[j], om);
            S[j] = S[j] * exp2f(M[j] - nmax) + os * exp2f(om - nmax);
            M[j] = nmax;
        }
    }

    __syncthreads();                                 // all LDS child-reads done
    float* red = reinterpret_cast<float*>(lds);      // [16][8][2]
    const int wid = threadIdx.x >> 6;
    if ((threadIdx.x & 63) == 0) {
        #pragma unroll
        for (int j = 0; j < 8; ++j) {
            red[(wid * 8 + j) * 2 + 0] = M[j];
            red[(wid * 8 + j) * 2 + 1] = S[j];
        }
    }
    __syncthreads();
    if (threadIdx.x < 8) {
        const int j = threadIdx.x;
        float Mm = -3.0e38f, Ss = 0.f;
        for (int w = 0; w < 16; ++w) {
            const float m_ = red[(w * 8 + j) * 2 + 0];
            const float s_ = red[(w * 8 + j) * 2 + 1];
            const float nmax = fmaxf(Mm, m_);
            Ss = Ss * exp2f(Mm - nmax) + s_ * exp2f(m_ - nmax);
            Mm = nmax;
        }
        pm[nc * B_ + bs * 8 + j] = Mm;
        ps[nc * B_ + bs * 8 + j] = Ss;
    }
}

// ---- root combine: 4 chunk partials per batch col, back to natural log ----
__global__ void root_comb_k(const float* __restrict__ pm,   // [NCHK][B]
                            const float* __restrict__ ps,
                            float* __restrict__ out)        // [B]
{
    const int b = blockIdx.x * blockDim.x + threadIdx.x;
    float M = -3.0e38f, S = 0.f;
    for (int c = 0; c < NCHK; ++c) {
        const float m_ = pm[c * B_ + b];
        const float s_ = ps[c * B_ + b];
        const float nmax = fmaxf(M, m_);
        S = S * exp2f(M - nmax) + s_ * exp2f(m_ - nmax);
        M = nmax;
    }
    out[b] = (M + log2f(S)) * LN2;
}

} // namespace

extern "C" void kernel_launch(void* const* d_in, const int* in_sizes, int n_in,
                              void* d_out, int out_size, void* d_ws, size_t ws_size,
                              hipStream_t stream) {
    const int*   inp = (const int*)d_in[0];     // [B,V]
    const float* lp  = (const float*)d_in[1];   // [V,K,C]
    const int*   pc  = (const int*)d_in[2];     // [L,E,PF]
    const int*   sc  = (const int*)d_in[3];     // [L,N,SF]
    const float* lw  = (const float*)d_in[4];   // [L,N,SF]
    const float* rw  = (const float*)d_in[5];   // [N]
    float*       out = (float*)d_out;           // [B,1]

    uint4*   nm0 = (uint4*)d_ws;                             // 8 MB
    uint4*   nm1 = nm0 + (size_t)NSLICE * N_;                // 8 MB
    ushort4* pcx = (ushort4*)(nm1 + (size_t)NSLICE * N_);    // 5 MB
    __half*  lwh = (__half*)(pcx + (size_t)L_ * N_ * SF_);   // 1.25 MB
    float*   pm  = (float*)(lwh + (size_t)L_ * N_ * SF_);    // [NCHK][B]
    float*   ps  = pm + (size_t)NCHK * B_;

    setup_k<<<(PREP_T + INPUT_T) / 256, 256, 0, stream>>>(
        sc, pc, lw, rw, inp, lp, pcx, lwh, nm0);

    for (int l = 0; l < L_ - 1; ++l) {
        const uint4* srcb = (l & 1) ? nm1 : nm0;
        uint4*       dstb = (l & 1) ? nm0 : nm1;
        layer_k<<<NSLICE * NCHK, 1024, 0, stream>>>(
            srcb,
            (const uint4*)(pcx + (size_t)l * N_ * SF_),
            (const uint4*)(lwh + (size_t)l * N_ * SF_),
            dstb);
    }
    // l = 4: last layer fused with root partial (rw folded into lwh)
    layer_last_k<<<NSLICE * NCHK, 1024, 0, stream>>>(
        nm0,
        (const uint4*)(pcx + (size_t)(L_ - 1) * N_ * SF_),
        (const uint4*)(lwh + (size_t)(L_ - 1) * N_ * SF_),
        pm, ps);

    root_comb_k<<<B_ / 256, 256, 0, stream>>>(pm, ps, out);
}

// Round 16
// 147.741 us; speedup vs baseline: 6.2136x; 1.1397x over previous
//
#include <hip/hip_runtime.h>
#include <hip/hip_fp16.h>

namespace {

constexpr int V_ = 256, K_ = 32, C_ = 256;
constexpr int N_ = V_ * K_;            // 8192 nodes per layer
constexpr int E_ = 32768, PF_ = 4, SF_ = 16, L_ = 5;
constexpr int B_ = 512;                // batch
constexpr int NSLICE = B_ / 8;         // 64 batch slices of 8
constexpr int NCHK = 4;                // node chunks per layer
constexpr int NPB = N_ / NCHK;         // 2048 nodes per block

constexpr int PREP_T  = L_ * N_ * SF_;     // 655360
constexpr int INPUT_T = NSLICE * N_;       // 524288

constexpr float LOG2E = 1.4426950408889634f;
constexpr float LN2   = 0.6931471805599453f;

typedef _Float16 h2v __attribute__((ext_vector_type(2)));  // packed f16

__device__ __forceinline__ uint32_t f2h(float a, float b) {
    __half2 h = __floats2half2_rn(a, b);
    return *reinterpret_cast<uint32_t*>(&h);
}
__device__ __forceinline__ h2v splat2h(uint32_t bits) {
    const _Float16 h = __builtin_bit_cast(_Float16, (unsigned short)(bits & 0xffffu));
    h2v r; r.x = h; r.y = h; return r;
}
__device__ __forceinline__ float2 h2f2(h2v v) {
    return make_float2((float)v.x, (float)v.y);
}
__device__ __forceinline__ h2v u2h(uint32_t u) { return __builtin_bit_cast(h2v, u); }

// ---- setup: prep (pcx/lwh, rw folded into layer-4) + input layer ----
__global__ void setup_k(const int* __restrict__ sc,    // [L,N,SF]
                        const int* __restrict__ pc,    // [L,E,PF]
                        const float* __restrict__ lw,  // [L,N,SF]
                        const float* __restrict__ rw,  // [N]
                        const int* __restrict__ inp,   // [B,V]
                        const float* __restrict__ lp,  // [V,K,C]
                        ushort4* __restrict__ pcx,     // [L,N,SF]
                        __half* __restrict__ lwh,      // [L,N,SF]
                        uint4* __restrict__ nm)        // [NSLICE][N]
{
    const int t = blockIdx.x * blockDim.x + threadIdx.x;
    if (t < PREP_T) {
        const int l = t >> 17;                         // / (N*SF)
        const int n = (t >> 4) & (N_ - 1);
        const int e = sc[t];
        const int4 p = *reinterpret_cast<const int4*>(pc + ((size_t)l * E_ + e) * 4);
        ushort4 u;
        u.x = (unsigned short)p.x; u.y = (unsigned short)p.y;
        u.z = (unsigned short)p.z; u.w = (unsigned short)p.w;
        pcx[t] = u;
        const float add = (l == L_ - 1) ? rw[n] : 0.f;
        lwh[t] = __float2half((lw[t] + add) * LOG2E);
    } else {
        const int t2 = t - PREP_T;                     // [0, NSLICE*N)
        const int vk = t2 & (N_ - 1);
        const int bs = t2 >> 13;
        const int v = vk >> 5;
        const int b = bs * 8;
        const float* row = lp + (size_t)vk * C_;
        uint4 r;
        r.x = f2h(row[inp[(b + 0) * V_ + v]] * LOG2E, row[inp[(b + 1) * V_ + v]] * LOG2E);
        r.y = f2h(row[inp[(b + 2) * V_ + v]] * LOG2E, row[inp[(b + 3) * V_ + v]] * LOG2E);
        r.z = f2h(row[inp[(b + 4) * V_ + v]] * LOG2E, row[inp[(b + 5) * V_ + v]] * LOG2E);
        r.w = f2h(row[inp[(b + 6) * V_ + v]] * LOG2E, row[inp[(b + 7) * V_ + v]] * LOG2E);
        nm[(size_t)bs * N_ + vk] = r;
    }
}

// stage 128KB slice: async direct-to-LDS (wave-uniform base + lane*16 layout).
// NOTE: no register round-trip -> lower VGPR pressure than plain copy.
__device__ __forceinline__ void stage_slice(uint4* lds, const uint4* src) {
#if __has_builtin(__builtin_amdgcn_global_load_lds)
    #pragma unroll
    for (int k = 0; k < 8; ++k) {
        const int i = threadIdx.x + k * 1024;
        __builtin_amdgcn_global_load_lds(
            (const __attribute__((address_space(1))) void*)(src + i),
            (__attribute__((address_space(3))) void*)(lds + i), 16, 0, 0);
    }
#else
    #pragma unroll
    for (int k = 0; k < 8; ++k) {
        const int i = threadIdx.x + k * 1024;
        lds[i] = src[i];
    }
#endif
    __syncthreads();   // compiler emits s_waitcnt vmcnt(0) before s_barrier
}

// one node's 16 children -> m2[4] (packed max), acc[8]; meta loaded INLINE
// (round-15 lesson: pre-hoisting meta into registers spills at the 64-VGPR budget)
__device__ __forceinline__ void node_lse(const uint4* lds, const uint4* pr, const uint4* wr,
                                         h2v m2[4], float acc[8])
{
    h2v xs[8][4], cm[4];

    auto children8 = [&](const uint4 pw0, const uint4 pw1, const uint4 pw2,
                         const uint4 pw3, const uint4 wv) {
        auto child = [&](int s8, uint32_t rr0, uint32_t rr1, uint32_t wbits) {
            const uint4 a = lds[rr0 & 0xffffu];
            const uint4 b = lds[rr0 >> 16];
            const uint4 c = lds[rr1 & 0xffffu];
            const uint4 d = lds[rr1 >> 16];
            const h2v w2 = splat2h(wbits);
            #pragma unroll
            for (int q = 0; q < 4; ++q) {
                h2v t = (u2h((&a.x)[q]) + u2h((&b.x)[q]))
                      + (u2h((&c.x)[q]) + u2h((&d.x)[q]));
                t = t + w2;
                xs[s8][q] = t;
                cm[q] = __builtin_elementwise_max(cm[q], t);
            }
        };
        child(0, pw0.x, pw0.y, wv.x);
        child(1, pw0.z, pw0.w, wv.x >> 16);
        child(2, pw1.x, pw1.y, wv.y);
        child(3, pw1.z, pw1.w, wv.y >> 16);
        child(4, pw2.x, pw2.y, wv.z);
        child(5, pw2.z, pw2.w, wv.z >> 16);
        child(6, pw3.x, pw3.y, wv.w);
        child(7, pw3.z, pw3.w, wv.w >> 16);
    };

    // ---- half 0 ----
    #pragma unroll
    for (int q = 0; q < 4; ++q) cm[q] = splat2h(0xF400u);  // f16 -16384
    children8(pr[0], pr[1], pr[2], pr[3], wr[0]);
    #pragma unroll
    for (int q = 0; q < 4; ++q) m2[q] = cm[q];
    #pragma unroll
    for (int j = 0; j < 8; ++j) acc[j] = 0.f;
    #pragma unroll
    for (int s = 0; s < 8; ++s) {
        #pragma unroll
        for (int q = 0; q < 4; ++q) {
            const float2 f = h2f2(xs[s][q] - m2[q]);
            acc[2 * q + 0] += exp2f(f.x);
            acc[2 * q + 1] += exp2f(f.y);
        }
    }

    // ---- half 1 ----
    #pragma unroll
    for (int q = 0; q < 4; ++q) cm[q] = splat2h(0xF400u);
    children8(pr[4], pr[5], pr[6], pr[7], wr[1]);
    #pragma unroll
    for (int q = 0; q < 4; ++q) {
        const h2v mm = __builtin_elementwise_max(m2[q], cm[q]);
        const float2 df = h2f2(m2[q] - mm);
        acc[2 * q + 0] *= exp2f(df.x);
        acc[2 * q + 1] *= exp2f(df.y);
        m2[q] = mm;
    }
    #pragma unroll
    for (int s = 0; s < 8; ++s) {
        #pragma unroll
        for (int q = 0; q < 4; ++q) {
            const float2 f = h2f2(xs[s][q] - m2[q]);
            acc[2 * q + 0] += exp2f(f.x);
            acc[2 * q + 1] += exp2f(f.y);
        }
    }
}

// ---- fused layer (layers 0..3), LDS-staged nm slice ----
__global__ __launch_bounds__(1024) void layer_k(
    const uint4* __restrict__ nmi,   // [NSLICE][N] rows of 8 f16 (log2 domain)
    const uint4* __restrict__ pcx,   // [N][8]
    const uint4* __restrict__ lwh,   // [N][2]
    uint4* __restrict__ nmo)         // [NSLICE][N]
{
    __shared__ uint4 lds[N_];                       // 128 KB
    const int bs = blockIdx.x & (NSLICE - 1);
    const int nc = blockIdx.x >> 6;

    stage_slice(lds, nmi + (size_t)bs * N_);

    #pragma unroll
    for (int r = 0; r < 2; ++r) {
        const int n = nc * NPB + r * 1024 + threadIdx.x;
        h2v m2[4];
        float acc[8];
        node_lse(lds, pcx + (size_t)n * 8, lwh + (size_t)n * 2, m2, acc);

        uint4 o;
        {
            const float2 f0 = h2f2(m2[0]);
            const float2 f1 = h2f2(m2[1]);
            o.x = f2h(f0.x + log2f(acc[0]), f0.y + log2f(acc[1]));
            o.y = f2h(f1.x + log2f(acc[2]), f1.y + log2f(acc[3]));
        }
        {
            const float2 f2v = h2f2(m2[2]);
            const float2 f3v = h2f2(m2[3]);
            o.z = f2h(f2v.x + log2f(acc[4]), f2v.y + log2f(acc[5]));
            o.w = f2h(f3v.x + log2f(acc[6]), f3v.y + log2f(acc[7]));
        }
        nmo[(size_t)bs * N_ + n] = o;
    }
}

// ---- last layer + root partial (rw folded into lwh; no nm5 materialization) ----
__global__ __launch_bounds__(1024) void layer_last_k(
    const uint4* __restrict__ nmi,   // [NSLICE][N]
    const uint4* __restrict__ pcx,   // [N][8]
    const uint4* __restrict__ lwh,   // [N][2] (includes rw)
    float* __restrict__ pm,          // [NCHK][B]
    float* __restrict__ ps)          // [NCHK][B]
{
    __shared__ uint4 lds[N_];                       // 128 KB
    const int bs = blockIdx.x & (NSLICE - 1);
    const int nc = blockIdx.x >> 6;

    stage_slice(lds, nmi + (size_t)bs * N_);

    // node 0 -> v0[8] (single f32 per column carried across second node_lse)
    float v0[8];
    {
        const int n = nc * NPB + threadIdx.x;
        h2v m2[4];
        float acc[8];
        node_lse(lds, pcx + (size_t)n * 8, lwh + (size_t)n * 2, m2, acc);
        #pragma unroll
        for (int q = 0; q < 4; ++q) {
            const float2 f = h2f2(m2[q]);
            v0[2 * q + 0] = f.x + log2f(acc[2 * q + 0]);
            v0[2 * q + 1] = f.y + log2f(acc[2 * q + 1]);
        }
    }
    // node 1 -> merge into (M, S)
    float M[8], S[8];
    {
        const int n = nc * NPB + 1024 + threadIdx.x;
        h2v m2[4];
        float acc[8];
        node_lse(lds, pcx + (size_t)n * 8, lwh + (size_t)n * 2, m2, acc);
        #pragma unroll
        for (int q = 0; q < 4; ++q) {
            const float2 f = h2f2(m2[q]);
            const float v1a = f.x + log2f(acc[2 * q + 0]);
            const float v1b = f.y + log2f(acc[2 * q + 1]);
            M[2 * q + 0] = fmaxf(v0[2 * q + 0], v1a);
            M[2 * q + 1] = fmaxf(v0[2 * q + 1], v1b);
            S[2 * q + 0] = exp2f(v0[2 * q + 0] - M[2 * q + 0]) + exp2f(v1a - M[2 * q + 0]);
            S[2 * q + 1] = exp2f(v0[2 * q + 1] - M[2 * q + 1]) + exp2f(v1b - M[2 * q + 1]);
        }
    }

    // 64-lane butterfly reduce
    for (int d = 1; d < 64; d <<= 1) {
        #pragma unroll
        for (int j = 0; j < 8; ++j) {
            const float om = __shfl_xor(M[j], d);
            const float os = __shfl_xor(S[j], d);
            const float nmax = fmaxf(M[j], om);
            S[j] = S[j] * exp2f(M[j] - nmax) + os * exp2f(om - nmax);
            M[j] = nmax;
        }
    }

    __syncthreads();                                 // all LDS child-reads done
    float* red = reinterpret_cast<float*>(lds);      // [16][8][2]
    const int wid = threadIdx.x >> 6;
    if ((threadIdx.x & 63) == 0) {
        #pragma unroll
        for (int j = 0; j < 8; ++j) {
            red[(wid * 8 + j) * 2 + 0] = M[j];
            red[(wid * 8 + j) * 2 + 1] = S[j];
        }
    }
    __syncthreads();
    if (threadIdx.x < 8) {
        const int j = threadIdx.x;
        float Mm = -3.0e38f, Ss = 0.f;
        for (int w = 0; w < 16; ++w) {
            const float m_ = red[(w * 8 + j) * 2 + 0];
            const float s_ = red[(w * 8 + j) * 2 + 1];
            const float nmax = fmaxf(Mm, m_);
            Ss = Ss * exp2f(Mm - nmax) + s_ * exp2f(m_ - nmax);
            Mm = nmax;
        }
        pm[nc * B_ + bs * 8 + j] = Mm;
        ps[nc * B_ + bs * 8 + j] = Ss;
    }
}

// ---- root combine: 4 chunk partials per batch col, back to natural log ----
__global__ void root_comb_k(const float* __restrict__ pm,   // [NCHK][B]
                            const float* __restrict__ ps,
                            float* __restrict__ out)        // [B]
{
    const int b = blockIdx.x * blockDim.x + threadIdx.x;
    float M = -3.0e38f, S = 0.f;
    for (int c = 0; c < NCHK; ++c) {
        const float m_ = pm[c * B_ + b];
        const float s_ = ps[c * B_ + b];
        const float nmax = fmaxf(M, m_);
        S = S * exp2f(M - nmax) + s_ * exp2f(m_ - nmax);
        M = nmax;
    }
    out[b] = (M + log2f(S)) * LN2;
}

} // namespace

extern "C" void kernel_launch(void* const* d_in, const int* in_sizes, int n_in,
                              void* d_out, int out_size, void* d_ws, size_t ws_size,
                              hipStream_t stream) {
    const int*   inp = (const int*)d_in[0];     // [B,V]
    const float* lp  = (const float*)d_in[1];   // [V,K,C]
    const int*   pc  = (const int*)d_in[2];     // [L,E,PF]
    const int*   sc  = (const int*)d_in[3];     // [L,N,SF]
    const float* lw  = (const float*)d_in[4];   // [L,N,SF]
    const float* rw  = (const float*)d_in[5];   // [N]
    float*       out = (float*)d_out;           // [B,1]

    uint4*   nm0 = (uint4*)d_ws;                             // 8 MB
    uint4*   nm1 = nm0 + (size_t)NSLICE * N_;                // 8 MB
    ushort4* pcx = (ushort4*)(nm1 + (size_t)NSLICE * N_);    // 5 MB
    __half*  lwh = (__half*)(pcx + (size_t)L_ * N_ * SF_);   // 1.25 MB
    float*   pm  = (float*)(lwh + (size_t)L_ * N_ * SF_);    // [NCHK][B]
    float*   ps  = pm + (size_t)NCHK * B_;

    setup_k<<<(PREP_T + INPUT_T) / 256, 256, 0, stream>>>(
        sc, pc, lw, rw, inp, lp, pcx, lwh, nm0);

    for (int l = 0; l < L_ - 1; ++l) {
        const uint4* srcb = (l & 1) ? nm1 : nm0;
        uint4*       dstb = (l & 1) ? nm0 : nm1;
        layer_k<<<NSLICE * NCHK, 1024, 0, stream>>>(
            srcb,
            (const uint4*)(pcx + (size_t)l * N_ * SF_),
            (const uint4*)(lwh + (size_t)l * N_ * SF_),
            dstb);
    }
    // l = 4: last layer fused with root partial (rw folded into lwh)
    layer_last_k<<<NSLICE * NCHK, 1024, 0, stream>>>(
        nm0,
        (const uint4*)(pcx + (size_t)(L_ - 1) * N_ * SF_),
        (const uint4*)(lwh + (size_t)(L_ - 1) * N_ * SF_),
        pm, ps);

    root_comb_k<<<B_ / 256, 256, 0, stream>>>(pm, ps, out);
}

// Round 17
// 142.879 us; speedup vs baseline: 6.4251x; 1.0340x over previous
//
#include <hip/hip_runtime.h>
#include <hip/hip_fp16.h>

namespace {

constexpr int V_ = 256, K_ = 32, C_ = 256;
constexpr int N_ = V_ * K_;            // 8192 nodes per layer
constexpr int E_ = 32768, PF_ = 4, SF_ = 16, L_ = 5;
constexpr int B_ = 512;                // batch
constexpr int NSLICE = B_ / 8;         // 64 batch slices of 8
constexpr int NCHK = 4;                // node chunks per layer
constexpr int NPB = N_ / NCHK;         // 2048 nodes per block

constexpr int PREP_T  = L_ * N_ * SF_;     // 655360
constexpr int INPUT_T = NSLICE * N_;       // 524288

constexpr float LOG2E = 1.4426950408889634f;
constexpr float LN2   = 0.6931471805599453f;

typedef _Float16 h2v __attribute__((ext_vector_type(2)));  // packed f16

__device__ __forceinline__ uint32_t f2h(float a, float b) {
    __half2 h = __floats2half2_rn(a, b);
    return *reinterpret_cast<uint32_t*>(&h);
}
__device__ __forceinline__ h2v splat2h(uint32_t bits) {
    const _Float16 h = __builtin_bit_cast(_Float16, (unsigned short)(bits & 0xffffu));
    h2v r; r.x = h; r.y = h; return r;
}
__device__ __forceinline__ float2 h2f2(h2v v) {
    return make_float2((float)v.x, (float)v.y);
}
__device__ __forceinline__ h2v u2h(uint32_t u) { return __builtin_bit_cast(h2v, u); }

// ---- setup: prep (pcx/lwh, rw folded into layer-4) + input layer ----
__global__ void setup_k(const int* __restrict__ sc,    // [L,N,SF]
                        const int* __restrict__ pc,    // [L,E,PF]
                        const float* __restrict__ lw,  // [L,N,SF]
                        const float* __restrict__ rw,  // [N]
                        const int* __restrict__ inp,   // [B,V]
                        const float* __restrict__ lp,  // [V,K,C]
                        ushort4* __restrict__ pcx,     // [L,N,SF]
                        __half* __restrict__ lwh,      // [L,N,SF]
                        uint4* __restrict__ nm)        // [NSLICE][N]
{
    const int t = blockIdx.x * blockDim.x + threadIdx.x;
    if (t < PREP_T) {
        const int l = t >> 17;                         // / (N*SF)
        const int n = (t >> 4) & (N_ - 1);
        const int e = sc[t];
        const int4 p = *reinterpret_cast<const int4*>(pc + ((size_t)l * E_ + e) * 4);
        ushort4 u;
        u.x = (unsigned short)p.x; u.y = (unsigned short)p.y;
        u.z = (unsigned short)p.z; u.w = (unsigned short)p.w;
        pcx[t] = u;
        const float add = (l == L_ - 1) ? rw[n] : 0.f;
        lwh[t] = __float2half((lw[t] + add) * LOG2E);
    } else {
        const int t2 = t - PREP_T;                     // [0, NSLICE*N)
        const int vk = t2 & (N_ - 1);
        const int bs = t2 >> 13;
        const int v = vk >> 5;
        const int b = bs * 8;
        const float* row = lp + (size_t)vk * C_;
        uint4 r;
        r.x = f2h(row[inp[(b + 0) * V_ + v]] * LOG2E, row[inp[(b + 1) * V_ + v]] * LOG2E);
        r.y = f2h(row[inp[(b + 2) * V_ + v]] * LOG2E, row[inp[(b + 3) * V_ + v]] * LOG2E);
        r.z = f2h(row[inp[(b + 4) * V_ + v]] * LOG2E, row[inp[(b + 5) * V_ + v]] * LOG2E);
        r.w = f2h(row[inp[(b + 6) * V_ + v]] * LOG2E, row[inp[(b + 7) * V_ + v]] * LOG2E);
        nm[(size_t)bs * N_ + vk] = r;
    }
}

// one node's 16 children -> m2[4] (packed max), acc[8]; meta loaded INLINE
// (round-15 lesson: pre-hoisting meta into registers spills at the 64-VGPR budget)
__device__ __forceinline__ void node_lse(const uint4* lds, const uint4* pr, const uint4* wr,
                                         h2v m2[4], float acc[8])
{
    h2v xs[8][4], cm[4];

    auto children8 = [&](const uint4 pw0, const uint4 pw1, const uint4 pw2,
                         const uint4 pw3, const uint4 wv) {
        auto child = [&](int s8, uint32_t rr0, uint32_t rr1, uint32_t wbits) {
            const uint4 a = lds[rr0 & 0xffffu];
            const uint4 b = lds[rr0 >> 16];
            const uint4 c = lds[rr1 & 0xffffu];
            const uint4 d = lds[rr1 >> 16];
            const h2v w2 = splat2h(wbits);
            #pragma unroll
            for (int q = 0; q < 4; ++q) {
                h2v t = (u2h((&a.x)[q]) + u2h((&b.x)[q]))
                      + (u2h((&c.x)[q]) + u2h((&d.x)[q]));
                t = t + w2;
                xs[s8][q] = t;
                cm[q] = __builtin_elementwise_max(cm[q], t);
            }
        };
        child(0, pw0.x, pw0.y, wv.x);
        child(1, pw0.z, pw0.w, wv.x >> 16);
        child(2, pw1.x, pw1.y, wv.y);
        child(3, pw1.z, pw1.w, wv.y >> 16);
        child(4, pw2.x, pw2.y, wv.z);
        child(5, pw2.z, pw2.w, wv.z >> 16);
        child(6, pw3.x, pw3.y, wv.w);
        child(7, pw3.z, pw3.w, wv.w >> 16);
    };

    // ---- half 0 ----
    #pragma unroll
    for (int q = 0; q < 4; ++q) cm[q] = splat2h(0xF400u);  // f16 -16384
    children8(pr[0], pr[1], pr[2], pr[3], wr[0]);
    #pragma unroll
    for (int q = 0; q < 4; ++q) m2[q] = cm[q];
    #pragma unroll
    for (int j = 0; j < 8; ++j) acc[j] = 0.f;
    #pragma unroll
    for (int s = 0; s < 8; ++s) {
        #pragma unroll
        for (int q = 0; q < 4; ++q) {
            const float2 f = h2f2(xs[s][q] - m2[q]);
            acc[2 * q + 0] += exp2f(f.x);
            acc[2 * q + 1] += exp2f(f.y);
        }
    }

    // ---- half 1 ----
    #pragma unroll
    for (int q = 0; q < 4; ++q) cm[q] = splat2h(0xF400u);
    children8(pr[4], pr[5], pr[6], pr[7], wr[1]);
    #pragma unroll
    for (int q = 0; q < 4; ++q) {
        const h2v mm = __builtin_elementwise_max(m2[q], cm[q]);
        const float2 df = h2f2(m2[q] - mm);
        acc[2 * q + 0] *= exp2f(df.x);
        acc[2 * q + 1] *= exp2f(df.y);
        m2[q] = mm;
    }
    #pragma unroll
    for (int s = 0; s < 8; ++s) {
        #pragma unroll
        for (int q = 0; q < 4; ++q) {
            const float2 f = h2f2(xs[s][q] - m2[q]);
            acc[2 * q + 0] += exp2f(f.x);
            acc[2 * q + 1] += exp2f(f.y);
        }
    }
}

// ---- fused layer (layers 0..3), LDS-staged nm slice (plain copy: fastest measured) ----
__global__ __launch_bounds__(1024) void layer_k(
    const uint4* __restrict__ nmi,   // [NSLICE][N] rows of 8 f16 (log2 domain)
    const uint4* __restrict__ pcx,   // [N][8]
    const uint4* __restrict__ lwh,   // [N][2]
    uint4* __restrict__ nmo)         // [NSLICE][N]
{
    __shared__ uint4 lds[N_];                       // 128 KB
    const int bs = blockIdx.x & (NSLICE - 1);
    const int nc = blockIdx.x >> 6;

    const uint4* src = nmi + (size_t)bs * N_;
    for (int i = threadIdx.x; i < N_; i += 1024) lds[i] = src[i];
    __syncthreads();

    #pragma unroll
    for (int r = 0; r < 2; ++r) {
        const int n = nc * NPB + r * 1024 + threadIdx.x;
        h2v m2[4];
        float acc[8];
        node_lse(lds, pcx + (size_t)n * 8, lwh + (size_t)n * 2, m2, acc);

        uint4 o;
        {
            const float2 f0 = h2f2(m2[0]);
            const float2 f1 = h2f2(m2[1]);
            o.x = f2h(f0.x + log2f(acc[0]), f0.y + log2f(acc[1]));
            o.y = f2h(f1.x + log2f(acc[2]), f1.y + log2f(acc[3]));
        }
        {
            const float2 f2v = h2f2(m2[2]);
            const float2 f3v = h2f2(m2[3]);
            o.z = f2h(f2v.x + log2f(acc[4]), f2v.y + log2f(acc[5]));
            o.w = f2h(f3v.x + log2f(acc[6]), f3v.y + log2f(acc[7]));
        }
        nmo[(size_t)bs * N_ + n] = o;
    }
}

// ---- last layer + root partial (rw folded into lwh; no nm5 materialization) ----
__global__ __launch_bounds__(1024) void layer_last_k(
    const uint4* __restrict__ nmi,   // [NSLICE][N]
    const uint4* __restrict__ pcx,   // [N][8]
    const uint4* __restrict__ lwh,   // [N][2] (includes rw)
    float* __restrict__ pm,          // [NCHK][B]
    float* __restrict__ ps)          // [NCHK][B]
{
    __shared__ uint4 lds[N_];                       // 128 KB
    const int bs = blockIdx.x & (NSLICE - 1);
    const int nc = blockIdx.x >> 6;

    const uint4* src = nmi + (size_t)bs * N_;
    for (int i = threadIdx.x; i < N_; i += 1024) lds[i] = src[i];
    __syncthreads();

    // node 0 -> v0[8] (single f32 per column carried across second node_lse)
    float v0[8];
    {
        const int n = nc * NPB + threadIdx.x;
        h2v m2[4];
        float acc[8];
        node_lse(lds, pcx + (size_t)n * 8, lwh + (size_t)n * 2, m2, acc);
        #pragma unroll
        for (int q = 0; q < 4; ++q) {
            const float2 f = h2f2(m2[q]);
            v0[2 * q + 0] = f.x + log2f(acc[2 * q + 0]);
            v0[2 * q + 1] = f.y + log2f(acc[2 * q + 1]);
        }
    }
    // node 1 -> merge into (M, S)
    float M[8], S[8];
    {
        const int n = nc * NPB + 1024 + threadIdx.x;
        h2v m2[4];
        float acc[8];
        node_lse(lds, pcx + (size_t)n * 8, lwh + (size_t)n * 2, m2, acc);
        #pragma unroll
        for (int q = 0; q < 4; ++q) {
            const float2 f = h2f2(m2[q]);
            const float v1a = f.x + log2f(acc[2 * q + 0]);
            const float v1b = f.y + log2f(acc[2 * q + 1]);
            M[2 * q + 0] = fmaxf(v0[2 * q + 0], v1a);
            M[2 * q + 1] = fmaxf(v0[2 * q + 1], v1b);
            S[2 * q + 0] = exp2f(v0[2 * q + 0] - M[2 * q + 0]) + exp2f(v1a - M[2 * q + 0]);
            S[2 * q + 1] = exp2f(v0[2 * q + 1] - M[2 * q + 1]) + exp2f(v1b - M[2 * q + 1]);
        }
    }

    // 64-lane butterfly reduce
    for (int d = 1; d < 64; d <<= 1) {
        #pragma unroll
        for (int j = 0; j < 8; ++j) {
            const float om = __shfl_xor(M[j], d);
            const float os = __shfl_xor(S[j], d);
            const float nmax = fmaxf(M[j], om);
            S[j] = S[j] * exp2f(M[j] - nmax) + os * exp2f(om - nmax);
            M[j] = nmax;
        }
    }

    __syncthreads();                                 // all LDS child-reads done
    float* red = reinterpret_cast<float*>(lds);      // [16][8][2]
    const int wid = threadIdx.x >> 6;
    if ((threadIdx.x & 63) == 0) {
        #pragma unroll
        for (int j = 0; j < 8; ++j) {
            red[(wid * 8 + j) * 2 + 0] = M[j];
            red[(wid * 8 + j) * 2 + 1] = S[j];
        }
    }
    __syncthreads();
    if (threadIdx.x < 8) {
        const int j = threadIdx.x;
        float Mm = -3.0e38f, Ss = 0.f;
        for (int w = 0; w < 16; ++w) {
            const float m_ = red[(w * 8 + j) * 2 + 0];
            const float s_ = red[(w * 8 + j) * 2 + 1];
            const float nmax = fmaxf(Mm, m_);
            Ss = Ss * exp2f(Mm - nmax) + s_ * exp2f(m_ - nmax);
            Mm = nmax;
        }
        pm[nc * B_ + bs * 8 + j] = Mm;
        ps[nc * B_ + bs * 8 + j] = Ss;
    }
}

// ---- root combine: 4 chunk partials per batch col, back to natural log ----
__global__ void root_comb_k(const float* __restrict__ pm,   // [NCHK][B]
                            const float* __restrict__ ps,
                            float* __restrict__ out)        // [B]
{
    const int b = blockIdx.x * blockDim.x + threadIdx.x;
    float M = -3.0e38f, S = 0.f;
    for (int c = 0; c < NCHK; ++c) {
        const float m_ = pm[c * B_ + b];
        const float s_ = ps[c * B_ + b];
        const float nmax = fmaxf(M, m_);
        S = S * exp2f(M - nmax) + s_ * exp2f(m_ - nmax);
        M = nmax;
    }
    out[b] = (M + log2f(S)) * LN2;
}

} // namespace

extern "C" void kernel_launch(void* const* d_in, const int* in_sizes, int n_in,
                              void* d_out, int out_size, void* d_ws, size_t ws_size,
                              hipStream_t stream) {
    const int*   inp = (const int*)d_in[0];     // [B,V]
    const float* lp  = (const float*)d_in[1];   // [V,K,C]
    const int*   pc  = (const int*)d_in[2];     // [L,E,PF]
    const int*   sc  = (const int*)d_in[3];     // [L,N,SF]
    const float* lw  = (const float*)d_in[4];   // [L,N,SF]
    const float* rw  = (const float*)d_in[5];   // [N]
    float*       out = (float*)d_out;           // [B,1]

    uint4*   nm0 = (uint4*)d_ws;                             // 8 MB
    uint4*   nm1 = nm0 + (size_t)NSLICE * N_;                // 8 MB
    ushort4* pcx = (ushort4*)(nm1 + (size_t)NSLICE * N_);    // 5 MB
    __half*  lwh = (__half*)(pcx + (size_t)L_ * N_ * SF_);   // 1.25 MB
    float*   pm  = (float*)(lwh + (size_t)L_ * N_ * SF_);    // [NCHK][B]
    float*   ps  = pm + (size_t)NCHK * B_;

    setup_k<<<(PREP_T + INPUT_T) / 256, 256, 0, stream>>>(
        sc, pc, lw, rw, inp, lp, pcx, lwh, nm0);

    for (int l = 0; l < L_ - 1; ++l) {
        const uint4* srcb = (l & 1) ? nm1 : nm0;
        uint4*       dstb = (l & 1) ? nm0 : nm1;
        layer_k<<<NSLICE * NCHK, 1024, 0, stream>>>(
            srcb,
            (const uint4*)(pcx + (size_t)l * N_ * SF_),
            (const uint4*)(lwh + (size_t)l * N_ * SF_),
            dstb);
    }
    // l = 4: last layer fused with root partial (rw folded into lwh)
    layer_last_k<<<NSLICE * NCHK, 1024, 0, stream>>>(
        nm0,
        (const uint4*)(pcx + (size_t)(L_ - 1) * N_ * SF_),
        (const uint4*)(lwh + (size_t)(L_ - 1) * N_ * SF_),
        pm, ps);

    root_comb_k<<<B_ / 256, 256, 0, stream>>>(pm, ps, out);
}